// Round 1
// baseline (11903.629 us; speedup 1.0000x reference)
//
#include <hip/hip_runtime.h>

#define D 64
#define R 4
#define H_ATT 32

// ---------------- degree count (once; same graph both layers) ----------------
__global__ void k_deg(const int* __restrict__ dst, float* __restrict__ deg, int E, int N) {
    int idx = blockIdx.x * blockDim.x + threadIdx.x;
    if (idx >= R * E) return;
    int r = idx / E;
    atomicAdd(&deg[r * N + dst[idx]], 1.0f);
}

// ---------------- xw = x @ W[r]  ([N,64] x [64,64]) ----------------
__global__ void k_matmul(const float* __restrict__ x, const float* __restrict__ W,
                         float* __restrict__ xw, int N) {
    __shared__ float Ws[64][64];
    __shared__ float xs[16][65];
    int t = threadIdx.x;
    for (int i = t; i < 4096; i += 256) Ws[i >> 6][i & 63] = W[i];
    int nb = blockIdx.x * 16;
    for (int i = t; i < 1024; i += 256) {
        int n = nb + (i >> 6);
        xs[i >> 6][i & 63] = (n < N) ? x[(size_t)n * D + (i & 63)] : 0.f;
    }
    __syncthreads();
    int ln = t >> 4, q = t & 15;
    int n = nb + ln;
    if (n >= N) return;
    float4 acc = {0.f, 0.f, 0.f, 0.f};
    for (int k = 0; k < 64; k++) {
        float xv = xs[ln][k];
        float4 wv = *reinterpret_cast<const float4*>(&Ws[k][q * 4]);
        acc.x += xv * wv.x; acc.y += xv * wv.y;
        acc.z += xv * wv.z; acc.w += xv * wv.w;
    }
    *reinterpret_cast<float4*>(&xw[(size_t)n * D + q * 4]) = acc;
}

// ---------------- scatter-add: h[dst, r, :] += xw[src, :] ----------------
__global__ void k_edge(const float* __restrict__ xw, const int* __restrict__ src,
                       const int* __restrict__ dst, float* __restrict__ h, int E, int r) {
    int idx = blockIdx.x * blockDim.x + threadIdx.x;
    if (idx >= E * 16) return;
    int e = idx >> 4, q = idx & 15;
    int s = src[e], d = dst[e];
    const float4 v = *reinterpret_cast<const float4*>(&xw[(size_t)s * D + q * 4]);
    float* hp = &h[((size_t)d * R + r) * D + q * 4];
    atomicAdd(hp + 0, v.x);
    atomicAdd(hp + 1, v.y);
    atomicAdd(hp + 2, v.z);
    atomicAdd(hp + 3, v.w);
}

// ---------------- normalize + bias + relu + attention score ----------------
// one wave per (n, r); block = 4 waves = one node's 4 relations
__global__ void k_norm_score(float* __restrict__ h, const float* __restrict__ deg,
                             const float* __restrict__ bias, const float* __restrict__ attW,
                             const float* __restrict__ attb, const float* __restrict__ attv,
                             float* __restrict__ wspread, int N) {
    int gw = (blockIdx.x * blockDim.x + threadIdx.x) >> 6;
    int lane = threadIdx.x & 63;
    int lw = threadIdx.x >> 6;
    int n = gw >> 2, r = gw & 3;
    __shared__ float vals[4][65];
    if (n >= N) return;
    float dg = deg[r * N + n];
    dg = dg < 1.f ? 1.f : dg;
    size_t off = ((size_t)n * R + r) * D + lane;
    float hv = h[off] / dg + bias[r * D + lane];
    hv = fmaxf(hv, 0.f);
    h[off] = hv;
    vals[lw][lane] = hv;
    // same-wave LDS dependency: compiler inserts lgkmcnt wait
    float sc = 0.f;
    if (lane < H_ATT) {
        float acc = attb[lane];
        for (int k = 0; k < 64; k++) acc += vals[lw][k] * attW[k * H_ATT + lane];
        sc = tanhf(acc) * attv[lane];
    }
    for (int o = 16; o > 0; o >>= 1) sc += __shfl_down(sc, o);
    if (lane == 0) atomicAdd(&wspread[r * 1024 + (n & 1023)], sc);
}

// ---------------- beta = softmax_r(mean_n w) ----------------
__global__ void k_beta(const float* __restrict__ wspread, float* __restrict__ beta, int N) {
    __shared__ float sums[4];
    int wid = threadIdx.x >> 6, lane = threadIdx.x & 63;
    float s = 0.f;
    for (int i = lane; i < 1024; i += 64) s += wspread[wid * 1024 + i];
    for (int o = 32; o > 0; o >>= 1) s += __shfl_down(s, o);
    if (lane == 0) sums[wid] = s;
    __syncthreads();
    if (threadIdx.x == 0) {
        float mean[R], m = -1e30f;
        for (int r = 0; r < R; r++) { mean[r] = sums[r] / (float)N; m = fmaxf(m, mean[r]); }
        float e[R], tot = 0.f;
        for (int r = 0; r < R; r++) { e[r] = expf(mean[r] - m); tot += e[r]; }
        for (int r = 0; r < R; r++) beta[r] = e[r] / tot;
    }
}

// ---------------- out[n,:] = sum_r beta[r] * h[n,r,:] ----------------
__global__ void k_combine(const float* __restrict__ h, const float* __restrict__ beta,
                          float* __restrict__ out, int N) {
    int idx = blockIdx.x * blockDim.x + threadIdx.x;
    int n = idx >> 4, q = idx & 15;
    if (n >= N) return;
    float b0 = beta[0], b1 = beta[1], b2 = beta[2], b3 = beta[3];
    const float4* hp = reinterpret_cast<const float4*>(&h[(size_t)n * R * D]);
    float4 v0 = hp[q], v1 = hp[16 + q], v2 = hp[32 + q], v3 = hp[48 + q];
    float4 o;
    o.x = b0 * v0.x + b1 * v1.x + b2 * v2.x + b3 * v3.x;
    o.y = b0 * v0.y + b1 * v1.y + b2 * v2.y + b3 * v3.y;
    o.z = b0 * v0.z + b1 * v1.z + b2 * v2.z + b3 * v3.z;
    o.w = b0 * v0.w + b1 * v1.w + b2 * v2.w + b3 * v3.w;
    reinterpret_cast<float4*>(out)[idx] = o;
}

extern "C" void kernel_launch(void* const* d_in, const int* in_sizes, int n_in,
                              void* d_out, int out_size, void* d_ws, size_t ws_size,
                              hipStream_t stream) {
    const float* x   = (const float*)d_in[0];
    const int*   src = (const int*)d_in[1];
    const int*   dst = (const int*)d_in[2];
    const float* W1  = (const float*)d_in[3];
    const float* b1  = (const float*)d_in[4];
    const float* a1W = (const float*)d_in[5];
    const float* a1b = (const float*)d_in[6];
    const float* a1v = (const float*)d_in[7];
    const float* W2  = (const float*)d_in[8];
    const float* b2  = (const float*)d_in[9];
    const float* a2W = (const float*)d_in[10];
    const float* a2b = (const float*)d_in[11];
    const float* a2v = (const float*)d_in[12];

    int N = in_sizes[0] / D;
    int E = in_sizes[1] / R;
    float* out = (float*)d_out;

    char* ws = (char*)d_ws;
    float* xw      = (float*)ws; ws += (size_t)N * D * 4;
    float* h       = (float*)ws; ws += (size_t)N * R * D * 4;
    float* deg     = (float*)ws; ws += (size_t)R * N * 4;
    float* wspread = (float*)ws; ws += (size_t)R * 1024 * 4;
    float* beta    = (float*)ws; ws += (size_t)R * 4;

    // degrees once (same graph both layers)
    hipMemsetAsync(deg, 0, (size_t)R * N * 4, stream);
    k_deg<<<(R * E + 255) / 256, 256, 0, stream>>>(dst, deg, E, N);

    for (int layer = 0; layer < 2; layer++) {
        const float* in = layer ? (const float*)out : x;
        const float* W  = layer ? W2 : W1;
        const float* bb = layer ? b2 : b1;
        const float* aW = layer ? a2W : a1W;
        const float* ab = layer ? a2b : a1b;
        const float* av = layer ? a2v : a1v;

        hipMemsetAsync(h, 0, (size_t)N * R * D * 4, stream);
        hipMemsetAsync(wspread, 0, (size_t)R * 1024 * 4, stream);

        for (int r = 0; r < R; r++) {
            k_matmul<<<(N + 15) / 16, 256, 0, stream>>>(in, W + (size_t)r * D * D, xw, N);
            k_edge<<<(int)(((size_t)E * 16 + 255) / 256), 256, 0, stream>>>(
                xw, src + (size_t)r * E, dst + (size_t)r * E, h, E, r);
        }
        k_norm_score<<<(int)(((size_t)N * R * 64 + 255) / 256), 256, 0, stream>>>(
            h, deg, bb, aW, ab, av, wspread, N);
        k_beta<<<1, 256, 0, stream>>>(wspread, beta, N);
        k_combine<<<(N * 16 + 255) / 256, 256, 0, stream>>>(h, beta, out, N);
    }
}

// Round 2
// 2260.258 us; speedup vs baseline: 5.2665x; 5.2665x over previous
//
#include <hip/hip_runtime.h>

#define D 64
#define R 4
#define H_ATT 32

// ============ CSR build (once per call; graph identical for both layers) ============

__global__ void k_degi(const int* __restrict__ dst, int* __restrict__ degi, int E, int N) {
    int idx = blockIdx.x * blockDim.x + threadIdx.x;
    if (idx >= R * E) return;
    int r = idx / E;
    atomicAdd(&degi[r * N + dst[idx]], 1);
}

// block-wise exclusive scan over 1024 entries/block
__global__ void k_scan_block(const int* __restrict__ in, int* __restrict__ out,
                             int* __restrict__ bsums, int total) {
    int t = threadIdx.x;
    int base = blockIdx.x * 1024;
    int v[4];
    for (int i = 0; i < 4; i++) {
        int idx = base + t * 4 + i;
        v[i] = (idx < total) ? in[idx] : 0;
    }
    int tsum = v[0] + v[1] + v[2] + v[3];
    int lane = t & 63, w = t >> 6;
    int x = tsum;
    for (int o = 1; o < 64; o <<= 1) {
        int y = __shfl_up(x, o);
        if (lane >= o) x += y;
    }
    __shared__ int wsum[4];
    if (lane == 63) wsum[w] = x;
    __syncthreads();
    int wbase = 0;
    for (int i = 0; i < w; i++) wbase += wsum[i];
    int excl = wbase + x - tsum;
    int run = excl;
    for (int i = 0; i < 4; i++) {
        int idx = base + t * 4 + i;
        if (idx < total) out[idx] = run;
        run += v[i];
    }
    if (t == 255) bsums[blockIdx.x] = excl + tsum;
}

__global__ void k_scan_bsums(int* __restrict__ bsums, int nb) {
    __shared__ int tmp[512];
    int t = threadIdx.x;
    for (int i = t; i < nb; i += 256) tmp[i] = bsums[i];
    __syncthreads();
    if (t == 0) {
        int run = 0;
        for (int i = 0; i < nb; i++) { int v = tmp[i]; tmp[i] = run; run += v; }
    }
    __syncthreads();
    for (int i = t; i < nb; i += 256) bsums[i] = tmp[i];
}

__global__ void k_scan_add(int* __restrict__ out, const int* __restrict__ bsums, int total) {
    int idx = blockIdx.x * blockDim.x + threadIdx.x;
    if (idx < total) out[idx] += bsums[idx >> 10];
}

__global__ void k_fill(const int* __restrict__ src, const int* __restrict__ dst,
                       int* __restrict__ cur, int* __restrict__ esrc, int E, int N) {
    int idx = blockIdx.x * blockDim.x + threadIdx.x;
    if (idx >= R * E) return;
    int r = idx / E;
    int pos = atomicAdd(&cur[r * N + dst[idx]], 1);
    esrc[pos] = src[idx];
}

// ============ per-layer kernels ============

// one block per node; wave w = relation w. agg[n,r,:] = (1/max(deg,1)) * sum_{src} xin[src,:]
__global__ void k_gather(const float* __restrict__ xin, const int* __restrict__ esrc,
                         const int* __restrict__ offs, const int* __restrict__ degi,
                         float* __restrict__ agg, int N) {
    int n = blockIdx.x;
    int w = threadIdx.x >> 6;
    int lane = threadIdx.x & 63;
    int idx = w * N + n;
    int eo = offs[idx];
    int cnt = degi[idx];
    float acc = 0.f;
    int j = 0;
    for (; j + 4 <= cnt; j += 4) {
        int s0 = esrc[eo + j], s1 = esrc[eo + j + 1];
        int s2 = esrc[eo + j + 2], s3 = esrc[eo + j + 3];
        float v0 = xin[(size_t)s0 * D + lane];
        float v1 = xin[(size_t)s1 * D + lane];
        float v2 = xin[(size_t)s2 * D + lane];
        float v3 = xin[(size_t)s3 * D + lane];
        acc += v0 + v1 + v2 + v3;
    }
    for (; j < cnt; j++) acc += xin[(size_t)esrc[eo + j] * D + lane];
    float inv = 1.f / fmaxf((float)cnt, 1.f);
    agg[((size_t)n * R + w) * D + lane] = acc * inv;
}

// h[n,r,:] = relu(agg[n,r,:] @ W[r] + b[r]); fused attention score -> wspread
// in-place safe: h may alias agg (tile staged to LDS before write)
__global__ void k_mm_score(const float* __restrict__ agg, const float* __restrict__ W,
                           const float* __restrict__ bias, const float* __restrict__ attW,
                           const float* __restrict__ attb, const float* __restrict__ attv,
                           float* __restrict__ h, float* __restrict__ wspread, int N) {
    int r = blockIdx.y;
    __shared__ float Ws[64][64];
    __shared__ float xs[16][65];
    int t = threadIdx.x;
    for (int i = t; i < 4096; i += 256) Ws[i >> 6][i & 63] = W[r * 4096 + i];
    int nb = blockIdx.x * 16;
    for (int i = t; i < 1024; i += 256) {
        int n = nb + (i >> 6);
        xs[i >> 6][i & 63] = (n < N) ? agg[((size_t)n * R + r) * D + (i & 63)] : 0.f;
    }
    __syncthreads();
    int ln = t >> 4, q = t & 15;
    int n = nb + ln;
    float4 acc = {0.f, 0.f, 0.f, 0.f};
    for (int k = 0; k < 64; k++) {
        float xv = xs[ln][k];
        float4 wv = *reinterpret_cast<const float4*>(&Ws[k][q * 4]);
        acc.x += xv * wv.x; acc.y += xv * wv.y;
        acc.z += xv * wv.z; acc.w += xv * wv.w;
    }
    float4 bv = *reinterpret_cast<const float4*>(&bias[r * D + q * 4]);
    acc.x = fmaxf(acc.x + bv.x, 0.f);
    acc.y = fmaxf(acc.y + bv.y, 0.f);
    acc.z = fmaxf(acc.z + bv.z, 0.f);
    acc.w = fmaxf(acc.w + bv.w, 0.f);
    if (n < N)
        *reinterpret_cast<float4*>(&h[((size_t)n * R + r) * D + q * 4]) = acc;
    __syncthreads();  // everyone done reading xs
    xs[ln][q * 4 + 0] = acc.x; xs[ln][q * 4 + 1] = acc.y;
    xs[ln][q * 4 + 2] = acc.z; xs[ln][q * 4 + 3] = acc.w;
    __syncthreads();
    // attention score: 16 threads per node, 2 hidden units each
    float sc = 0.f;
    if (n < N) {
        for (int mm = 0; mm < 2; mm++) {
            int m = q * 2 + mm;
            float a = attb[m];
            for (int k = 0; k < 64; k++) a += xs[ln][k] * attW[k * H_ATT + m];
            sc += tanhf(a) * attv[m];
        }
    }
    for (int o = 8; o > 0; o >>= 1) sc += __shfl_down(sc, o, 16);
    if (q == 0 && n < N) atomicAdd(&wspread[r * 1024 + (n & 1023)], sc);
}

__global__ void k_beta(const float* __restrict__ wspread, float* __restrict__ beta, int N) {
    __shared__ float sums[4];
    int wid = threadIdx.x >> 6, lane = threadIdx.x & 63;
    float s = 0.f;
    for (int i = lane; i < 1024; i += 64) s += wspread[wid * 1024 + i];
    for (int o = 32; o > 0; o >>= 1) s += __shfl_down(s, o);
    if (lane == 0) sums[wid] = s;
    __syncthreads();
    if (threadIdx.x == 0) {
        float mean[R], m = -1e30f;
        for (int r = 0; r < R; r++) { mean[r] = sums[r] / (float)N; m = fmaxf(m, mean[r]); }
        float e[R], tot = 0.f;
        for (int r = 0; r < R; r++) { e[r] = expf(mean[r] - m); tot += e[r]; }
        for (int r = 0; r < R; r++) beta[r] = e[r] / tot;
    }
}

__global__ void k_combine(const float* __restrict__ h, const float* __restrict__ beta,
                          float* __restrict__ out, int N) {
    int idx = blockIdx.x * blockDim.x + threadIdx.x;
    int n = idx >> 4, q = idx & 15;
    if (n >= N) return;
    float b0 = beta[0], b1 = beta[1], b2 = beta[2], b3 = beta[3];
    const float4* hp = reinterpret_cast<const float4*>(&h[(size_t)n * R * D]);
    float4 v0 = hp[q], v1 = hp[16 + q], v2 = hp[32 + q], v3 = hp[48 + q];
    float4 o;
    o.x = b0 * v0.x + b1 * v1.x + b2 * v2.x + b3 * v3.x;
    o.y = b0 * v0.y + b1 * v1.y + b2 * v2.y + b3 * v3.y;
    o.z = b0 * v0.z + b1 * v1.z + b2 * v2.z + b3 * v3.z;
    o.w = b0 * v0.w + b1 * v1.w + b2 * v2.w + b3 * v3.w;
    reinterpret_cast<float4*>(out)[idx] = o;
}

extern "C" void kernel_launch(void* const* d_in, const int* in_sizes, int n_in,
                              void* d_out, int out_size, void* d_ws, size_t ws_size,
                              hipStream_t stream) {
    const float* x   = (const float*)d_in[0];
    const int*   src = (const int*)d_in[1];
    const int*   dst = (const int*)d_in[2];
    const float* W1  = (const float*)d_in[3];
    const float* b1  = (const float*)d_in[4];
    const float* a1W = (const float*)d_in[5];
    const float* a1b = (const float*)d_in[6];
    const float* a1v = (const float*)d_in[7];
    const float* W2  = (const float*)d_in[8];
    const float* b2  = (const float*)d_in[9];
    const float* a2W = (const float*)d_in[10];
    const float* a2b = (const float*)d_in[11];
    const float* a2v = (const float*)d_in[12];

    int N = in_sizes[0] / D;
    int E = in_sizes[1] / R;
    int RN = R * N;
    float* out = (float*)d_out;

    char* ws = (char*)d_ws;
    float* agg     = (float*)ws; ws += (size_t)N * R * D * 4;   // aliased as h after k_mm_score
    int*   degi    = (int*)ws;   ws += (size_t)RN * 4;
    int*   offs    = (int*)ws;   ws += (size_t)RN * 4;
    int*   cur     = (int*)ws;   ws += (size_t)RN * 4;
    int*   esrc    = (int*)ws;   ws += (size_t)R * E * 4;
    int*   bsums   = (int*)ws;   ws += 4096;
    float* wspread = (float*)ws; ws += (size_t)R * 1024 * 4;
    float* beta    = (float*)ws; ws += 64;

    // ---- CSR build ----
    hipMemsetAsync(degi, 0, (size_t)RN * 4, stream);
    k_degi<<<(R * E + 255) / 256, 256, 0, stream>>>(dst, degi, E, N);
    int nb1024 = (RN + 1023) / 1024;
    k_scan_block<<<nb1024, 256, 0, stream>>>(degi, offs, bsums, RN);
    k_scan_bsums<<<1, 256, 0, stream>>>(bsums, nb1024);
    k_scan_add<<<(RN + 255) / 256, 256, 0, stream>>>(offs, bsums, RN);
    hipMemcpyAsync(cur, offs, (size_t)RN * 4, hipMemcpyDeviceToDevice, stream);
    k_fill<<<(R * E + 255) / 256, 256, 0, stream>>>(src, dst, cur, esrc, E, N);

    for (int layer = 0; layer < 2; layer++) {
        const float* in = layer ? (const float*)out : x;
        const float* W  = layer ? W2 : W1;
        const float* bb = layer ? b2 : b1;
        const float* aW = layer ? a2W : a1W;
        const float* ab = layer ? a2b : a1b;
        const float* av = layer ? a2v : a1v;

        hipMemsetAsync(wspread, 0, (size_t)R * 1024 * 4, stream);
        k_gather<<<N, 256, 0, stream>>>(in, esrc, offs, degi, agg, N);
        k_mm_score<<<dim3((N + 15) / 16, R), 256, 0, stream>>>(
            agg, W, bb, aW, ab, av, agg /*in-place*/, wspread, N);
        k_beta<<<1, 256, 0, stream>>>(wspread, beta, N);
        k_combine<<<(N * 16 + 255) / 256, 256, 0, stream>>>(agg, beta, out, N);
    }
}

// Round 3
// 1853.414 us; speedup vs baseline: 6.4225x; 1.2195x over previous
//
#include <hip/hip_runtime.h>

#define D 64
#define R 4
#define H_ATT 32
#define NPART 8

// ============ CSR build (once per call; graph identical for both layers) ============

// count degrees AND record each edge's arrival rank (coalesced write)
__global__ void k_degi_rank(const int* __restrict__ dst, int* __restrict__ degi,
                            int* __restrict__ rank, int E, int N) {
    int i = blockIdx.x * blockDim.x + threadIdx.x;
    int r = blockIdx.y;
    if (i >= E) return;
    size_t idx = (size_t)r * E + i;
    rank[idx] = atomicAdd(&degi[r * N + dst[idx]], 1);
}

// block-wise exclusive scan over 1024 entries/block
__global__ void k_scan_block(const int* __restrict__ in, int* __restrict__ out,
                             int* __restrict__ bsums, int total) {
    int t = threadIdx.x;
    int base = blockIdx.x * 1024;
    int v[4];
    for (int i = 0; i < 4; i++) {
        int idx = base + t * 4 + i;
        v[i] = (idx < total) ? in[idx] : 0;
    }
    int tsum = v[0] + v[1] + v[2] + v[3];
    int lane = t & 63, w = t >> 6;
    int x = tsum;
    for (int o = 1; o < 64; o <<= 1) {
        int y = __shfl_up(x, o);
        if (lane >= o) x += y;
    }
    __shared__ int wsum[4];
    if (lane == 63) wsum[w] = x;
    __syncthreads();
    int wbase = 0;
    for (int i = 0; i < w; i++) wbase += wsum[i];
    int excl = wbase + x - tsum;
    int run = excl;
    for (int i = 0; i < 4; i++) {
        int idx = base + t * 4 + i;
        if (idx < total) out[idx] = run;
        run += v[i];
    }
    if (t == 255) bsums[blockIdx.x] = excl + tsum;
}

__global__ void k_scan_bsums(int* __restrict__ bsums, int nb) {
    __shared__ int tmp[512];
    int t = threadIdx.x;
    for (int i = t; i < nb; i += 256) tmp[i] = bsums[i];
    __syncthreads();
    if (t == 0) {
        int run = 0;
        for (int i = 0; i < nb; i++) { int v = tmp[i]; tmp[i] = run; run += v; }
    }
    __syncthreads();
    for (int i = t; i < nb; i += 256) bsums[i] = tmp[i];
}

__global__ void k_scan_add(int* __restrict__ out, const int* __restrict__ bsums, int total) {
    int idx = blockIdx.x * blockDim.x + threadIdx.x;
    if (idx < total) out[idx] += bsums[idx >> 10];
}

// XCD-partitioned fill: partition p (= blockIdx&7 -> XCD p) only writes esrc
// positions for dst nodes in its range, keeping scattered stores L2-resident.
// Partition map is approximate (float); positions offs+rank are exact and
// partition-independent, so misassignment at range boundaries is still correct.
__global__ void k_fill_part(const int* __restrict__ src, const int* __restrict__ dst,
                            const int* __restrict__ rank, const int* __restrict__ offs,
                            int* __restrict__ esrc, int E, int N, float pscale) {
    int part = blockIdx.x & (NPART - 1);
    int bi = blockIdx.x >> 3;
    int nb = gridDim.x >> 3;
    int stride = nb * 256;
    for (int r = 0; r < R; r++) {
        const int* dstr = dst + (size_t)r * E;
        const int* srcr = src + (size_t)r * E;
        const int* rnkr = rank + (size_t)r * E;
        const int* offr = offs + r * N;
        for (int i = bi * 256 + threadIdx.x; i < E; i += stride) {
            int d = dstr[i];
            int p = (int)((float)d * pscale);
            p = p > (NPART - 1) ? (NPART - 1) : p;
            if (p != part) continue;
            esrc[offr[d] + rnkr[i]] = srcr[i];
        }
    }
}

// ============ per-layer kernels ============

// one block per node; wave w = relation w. agg[n,r,:] = (1/max(deg,1)) * sum_{src} xin[src,:]
__global__ void k_gather(const float* __restrict__ xin, const int* __restrict__ esrc,
                         const int* __restrict__ offs, const int* __restrict__ degi,
                         float* __restrict__ agg, int N) {
    int n = blockIdx.x;
    int w = threadIdx.x >> 6;
    int lane = threadIdx.x & 63;
    int idx = w * N + n;
    int eo = offs[idx];
    int cnt = degi[idx];
    float acc = 0.f;
    int j = 0;
    for (; j + 4 <= cnt; j += 4) {
        int s0 = esrc[eo + j], s1 = esrc[eo + j + 1];
        int s2 = esrc[eo + j + 2], s3 = esrc[eo + j + 3];
        float v0 = xin[(size_t)s0 * D + lane];
        float v1 = xin[(size_t)s1 * D + lane];
        float v2 = xin[(size_t)s2 * D + lane];
        float v3 = xin[(size_t)s3 * D + lane];
        acc += v0 + v1 + v2 + v3;
    }
    for (; j < cnt; j++) acc += xin[(size_t)esrc[eo + j] * D + lane];
    float inv = 1.f / fmaxf((float)cnt, 1.f);
    agg[((size_t)n * R + w) * D + lane] = acc * inv;
}

// h[n,r,:] = relu(agg[n,r,:] @ W[r] + b[r]); fused attention score -> wspread
__global__ void k_mm_score(const float* __restrict__ agg, const float* __restrict__ W,
                           const float* __restrict__ bias, const float* __restrict__ attW,
                           const float* __restrict__ attb, const float* __restrict__ attv,
                           float* __restrict__ h, float* __restrict__ wspread, int N) {
    int r = blockIdx.y;
    __shared__ float Ws[64][64];
    __shared__ float xs[16][65];
    int t = threadIdx.x;
    for (int i = t; i < 4096; i += 256) Ws[i >> 6][i & 63] = W[r * 4096 + i];
    int nb = blockIdx.x * 16;
    for (int i = t; i < 1024; i += 256) {
        int n = nb + (i >> 6);
        xs[i >> 6][i & 63] = (n < N) ? agg[((size_t)n * R + r) * D + (i & 63)] : 0.f;
    }
    __syncthreads();
    int ln = t >> 4, q = t & 15;
    int n = nb + ln;
    float4 acc = {0.f, 0.f, 0.f, 0.f};
    for (int k = 0; k < 64; k++) {
        float xv = xs[ln][k];
        float4 wv = *reinterpret_cast<const float4*>(&Ws[k][q * 4]);
        acc.x += xv * wv.x; acc.y += xv * wv.y;
        acc.z += xv * wv.z; acc.w += xv * wv.w;
    }
    float4 bv = *reinterpret_cast<const float4*>(&bias[r * D + q * 4]);
    acc.x = fmaxf(acc.x + bv.x, 0.f);
    acc.y = fmaxf(acc.y + bv.y, 0.f);
    acc.z = fmaxf(acc.z + bv.z, 0.f);
    acc.w = fmaxf(acc.w + bv.w, 0.f);
    if (n < N)
        *reinterpret_cast<float4*>(&h[((size_t)n * R + r) * D + q * 4]) = acc;
    __syncthreads();
    xs[ln][q * 4 + 0] = acc.x; xs[ln][q * 4 + 1] = acc.y;
    xs[ln][q * 4 + 2] = acc.z; xs[ln][q * 4 + 3] = acc.w;
    __syncthreads();
    float sc = 0.f;
    if (n < N) {
        for (int mm = 0; mm < 2; mm++) {
            int m = q * 2 + mm;
            float a = attb[m];
            for (int k = 0; k < 64; k++) a += xs[ln][k] * attW[k * H_ATT + m];
            sc += tanhf(a) * attv[m];
        }
    }
    for (int o = 8; o > 0; o >>= 1) sc += __shfl_down(sc, o, 16);
    if (q == 0 && n < N) atomicAdd(&wspread[r * 1024 + (n & 1023)], sc);
}

__global__ void k_beta(const float* __restrict__ wspread, float* __restrict__ beta, int N) {
    __shared__ float sums[4];
    int wid = threadIdx.x >> 6, lane = threadIdx.x & 63;
    float s = 0.f;
    for (int i = lane; i < 1024; i += 64) s += wspread[wid * 1024 + i];
    for (int o = 32; o > 0; o >>= 1) s += __shfl_down(s, o);
    if (lane == 0) sums[wid] = s;
    __syncthreads();
    if (threadIdx.x == 0) {
        float mean[R], m = -1e30f;
        for (int r = 0; r < R; r++) { mean[r] = sums[r] / (float)N; m = fmaxf(m, mean[r]); }
        float e[R], tot = 0.f;
        for (int r = 0; r < R; r++) { e[r] = expf(mean[r] - m); tot += e[r]; }
        for (int r = 0; r < R; r++) beta[r] = e[r] / tot;
    }
}

__global__ void k_combine(const float* __restrict__ h, const float* __restrict__ beta,
                          float* __restrict__ out, int N) {
    int idx = blockIdx.x * blockDim.x + threadIdx.x;
    int n = idx >> 4, q = idx & 15;
    if (n >= N) return;
    float b0 = beta[0], b1 = beta[1], b2 = beta[2], b3 = beta[3];
    const float4* hp = reinterpret_cast<const float4*>(&h[(size_t)n * R * D]);
    float4 v0 = hp[q], v1 = hp[16 + q], v2 = hp[32 + q], v3 = hp[48 + q];
    float4 o;
    o.x = b0 * v0.x + b1 * v1.x + b2 * v2.x + b3 * v3.x;
    o.y = b0 * v0.y + b1 * v1.y + b2 * v2.y + b3 * v3.y;
    o.z = b0 * v0.z + b1 * v1.z + b2 * v2.z + b3 * v3.z;
    o.w = b0 * v0.w + b1 * v1.w + b2 * v2.w + b3 * v3.w;
    reinterpret_cast<float4*>(out)[idx] = o;
}

extern "C" void kernel_launch(void* const* d_in, const int* in_sizes, int n_in,
                              void* d_out, int out_size, void* d_ws, size_t ws_size,
                              hipStream_t stream) {
    const float* x   = (const float*)d_in[0];
    const int*   src = (const int*)d_in[1];
    const int*   dst = (const int*)d_in[2];
    const float* W1  = (const float*)d_in[3];
    const float* b1  = (const float*)d_in[4];
    const float* a1W = (const float*)d_in[5];
    const float* a1b = (const float*)d_in[6];
    const float* a1v = (const float*)d_in[7];
    const float* W2  = (const float*)d_in[8];
    const float* b2  = (const float*)d_in[9];
    const float* a2W = (const float*)d_in[10];
    const float* a2b = (const float*)d_in[11];
    const float* a2v = (const float*)d_in[12];

    int N = in_sizes[0] / D;
    int E = in_sizes[1] / R;
    int RN = R * N;
    float* out = (float*)d_out;

    char* ws = (char*)d_ws;
    float* agg     = (float*)ws; ws += (size_t)N * R * D * 4;
    int*   degi    = (int*)ws;   ws += (size_t)RN * 4;
    int*   offs    = (int*)ws;   ws += (size_t)RN * 4;
    int*   esrc    = (int*)ws;   ws += (size_t)R * E * 4;
    int*   bsums   = (int*)ws;   ws += 4096;
    float* wspread = (float*)ws; ws += (size_t)R * 1024 * 4;
    float* beta    = (float*)ws; ws += 64;
    // rank is consumed by k_fill_part before k_gather writes agg -> alias
    int*   rank    = (int*)agg;

    // ---- CSR build ----
    hipMemsetAsync(degi, 0, (size_t)RN * 4, stream);
    k_degi_rank<<<dim3((E + 255) / 256, R), 256, 0, stream>>>(dst, degi, rank, E, N);
    int nb1024 = (RN + 1023) / 1024;
    k_scan_block<<<nb1024, 256, 0, stream>>>(degi, offs, bsums, RN);
    k_scan_bsums<<<1, 256, 0, stream>>>(bsums, nb1024);
    k_scan_add<<<(RN + 255) / 256, 256, 0, stream>>>(offs, bsums, RN);
    k_fill_part<<<NPART * 128, 256, 0, stream>>>(src, dst, rank, offs, esrc, E, N,
                                                 (float)NPART / (float)N);

    for (int layer = 0; layer < 2; layer++) {
        const float* in = layer ? (const float*)out : x;
        const float* W  = layer ? W2 : W1;
        const float* bb = layer ? b2 : b1;
        const float* aW = layer ? a2W : a1W;
        const float* ab = layer ? a2b : a1b;
        const float* av = layer ? a2v : a1v;

        hipMemsetAsync(wspread, 0, (size_t)R * 1024 * 4, stream);
        k_gather<<<N, 256, 0, stream>>>(in, esrc, offs, degi, agg, N);
        k_mm_score<<<dim3((N + 15) / 16, R), 256, 0, stream>>>(
            agg, W, bb, aW, ab, av, agg /*in-place*/, wspread, N);
        k_beta<<<1, 256, 0, stream>>>(wspread, beta, N);
        k_combine<<<(N * 16 + 255) / 256, 256, 0, stream>>>(agg, beta, out, N);
    }
}

// Round 4
// 1071.495 us; speedup vs baseline: 11.1094x; 1.7297x over previous
//
#include <hip/hip_runtime.h>

#define D 64
#define R 4
#define H_ATT 32
#define NPART 8

typedef __bf16 bf16x4 __attribute__((ext_vector_type(4)));
typedef __bf16 bf16x8 __attribute__((ext_vector_type(8)));
typedef float f32x4 __attribute__((ext_vector_type(4)));

// ============ CSR build (once per call; graph identical for both layers) ============

__global__ void k_degi_rank(const int* __restrict__ dst, int* __restrict__ degi,
                            int* __restrict__ rank, int E, int N) {
    int i = blockIdx.x * blockDim.x + threadIdx.x;
    int r = blockIdx.y;
    if (i >= E) return;
    size_t idx = (size_t)r * E + i;
    rank[idx] = atomicAdd(&degi[r * N + dst[idx]], 1);
}

__global__ void k_scan_block(const int* __restrict__ in, int* __restrict__ out,
                             int* __restrict__ bsums, int total) {
    int t = threadIdx.x;
    int base = blockIdx.x * 1024;
    int v[4];
    for (int i = 0; i < 4; i++) {
        int idx = base + t * 4 + i;
        v[i] = (idx < total) ? in[idx] : 0;
    }
    int tsum = v[0] + v[1] + v[2] + v[3];
    int lane = t & 63, w = t >> 6;
    int x = tsum;
    for (int o = 1; o < 64; o <<= 1) {
        int y = __shfl_up(x, o);
        if (lane >= o) x += y;
    }
    __shared__ int wsum[4];
    if (lane == 63) wsum[w] = x;
    __syncthreads();
    int wbase = 0;
    for (int i = 0; i < w; i++) wbase += wsum[i];
    int excl = wbase + x - tsum;
    int run = excl;
    for (int i = 0; i < 4; i++) {
        int idx = base + t * 4 + i;
        if (idx < total) out[idx] = run;
        run += v[i];
    }
    if (t == 255) bsums[blockIdx.x] = excl + tsum;
}

__global__ void k_scan_bsums(int* __restrict__ bsums, int nb) {
    __shared__ int tmp[512];
    int t = threadIdx.x;
    for (int i = t; i < nb; i += 256) tmp[i] = bsums[i];
    __syncthreads();
    if (t == 0) {
        int run = 0;
        for (int i = 0; i < nb; i++) { int v = tmp[i]; tmp[i] = run; run += v; }
    }
    __syncthreads();
    for (int i = t; i < nb; i += 256) bsums[i] = tmp[i];
}

__global__ void k_scan_add(int* __restrict__ out, const int* __restrict__ bsums, int total) {
    int idx = blockIdx.x * blockDim.x + threadIdx.x;
    if (idx < total) out[idx] += bsums[idx >> 10];
}

__global__ void k_fill_part(const int* __restrict__ src, const int* __restrict__ dst,
                            const int* __restrict__ rank, const int* __restrict__ offs,
                            int* __restrict__ esrc, int E, int N, float pscale) {
    int part = blockIdx.x & (NPART - 1);
    int bi = blockIdx.x >> 3;
    int nb = gridDim.x >> 3;
    int stride = nb * 256;
    for (int r = 0; r < R; r++) {
        const int* dstr = dst + (size_t)r * E;
        const int* srcr = src + (size_t)r * E;
        const int* rnkr = rank + (size_t)r * E;
        const int* offr = offs + r * N;
        for (int i = bi * 256 + threadIdx.x; i < E; i += stride) {
            int d = dstr[i];
            int p = (int)((float)d * pscale);
            p = p > (NPART - 1) ? (NPART - 1) : p;
            if (p != part) continue;
            esrc[offr[d] + rnkr[i]] = srcr[i];
        }
    }
}

// ============ weight precompute: transposed bf16 hi/lo (once per call) ============
// WtHi/WtLo layout: [layer][r][c][k]  (c = output col, k contiguous)
// attWtHi layout:   [layer][m][k]
__global__ void k_prep(const float* __restrict__ W1, const float* __restrict__ W2,
                       const float* __restrict__ a1W, const float* __restrict__ a2W,
                       __bf16* __restrict__ WtHi, __bf16* __restrict__ WtLo,
                       __bf16* __restrict__ attWtHi) {
    int idx = blockIdx.x * 256 + threadIdx.x;
    if (idx < 32768) {
        int layer = idx >> 14;
        int rem = idx & 16383;
        int r = rem >> 12;
        int ce = rem & 4095;
        int c = ce >> 6, k = ce & 63;
        const float* W = layer ? W2 : W1;
        float w = W[r * 4096 + k * 64 + c];
        __bf16 hi = (__bf16)w;
        __bf16 lo = (__bf16)(w - (float)hi);
        WtHi[idx] = hi;
        WtLo[idx] = lo;
    } else if (idx < 32768 + 4096) {
        int i2 = idx - 32768;
        int layer = i2 >> 11;
        int rem = i2 & 2047;
        int m = rem >> 6, k = rem & 63;
        const float* aW = layer ? a2W : a1W;
        attWtHi[i2] = (__bf16)(aW[k * H_ATT + m]);
    }
}

// ============ per-layer kernels ============

// one block per node; wave w = relation w
__global__ void k_gather(const float* __restrict__ xin, const int* __restrict__ esrc,
                         const int* __restrict__ offs, const int* __restrict__ degi,
                         float* __restrict__ agg, int N) {
    int n = blockIdx.x;
    int w = threadIdx.x >> 6;
    int lane = threadIdx.x & 63;
    int idx = w * N + n;
    int eo = offs[idx];
    int cnt = degi[idx];
    float acc = 0.f;
    int j = 0;
    for (; j + 4 <= cnt; j += 4) {
        int s0 = esrc[eo + j], s1 = esrc[eo + j + 1];
        int s2 = esrc[eo + j + 2], s3 = esrc[eo + j + 3];
        float v0 = xin[(size_t)s0 * D + lane];
        float v1 = xin[(size_t)s1 * D + lane];
        float v2 = xin[(size_t)s2 * D + lane];
        float v3 = xin[(size_t)s3 * D + lane];
        acc += v0 + v1 + v2 + v3;
    }
    for (; j < cnt; j++) acc += xin[(size_t)esrc[eo + j] * D + lane];
    float inv = 1.f / fmaxf((float)cnt, 1.f);
    agg[((size_t)n * R + w) * D + lane] = acc * inv;
}

// Fused: h = relu(agg @ W[r] + b[r]) via split-bf16 MFMA; score via bf16 MFMA.
// In-place: hbuf == agg (block reads its rows before writing them).
#define OFF_A_HI 0
#define OFF_A_LO 8192
#define OFF_B_HI 16384
#define OFF_B_LO 24576
#define OFF_ATTW 32768
__global__ __launch_bounds__(256) void k_rgemm(
        float* hbuf, const __bf16* __restrict__ WtHi, const __bf16* __restrict__ WtLo,
        const __bf16* __restrict__ attWHi, const float* __restrict__ bias,
        const float* __restrict__ attb, const float* __restrict__ attv,
        float* __restrict__ wspread, int N) {
    __shared__ __align__(16) char L[36864];
    float* hs = (float*)L;              // fp32 h stage [64][68], overlays A/B after GEMM
    int t = threadIdx.x;
    int r = blockIdx.y;
    int n0 = blockIdx.x * 64;

    // ---- stage A (agg rows) as swizzled bf16 hi/lo ----
    for (int rep = 0; rep < 4; rep++) {
        int row = rep * 16 + (t >> 4);
        int kq = (t & 15) * 4;
        float4 v = {0.f, 0.f, 0.f, 0.f};
        if (n0 + row < N)
            v = *reinterpret_cast<const float4*>(&hbuf[((size_t)(n0 + row) * R + r) * D + kq]);
        bf16x4 hv, lv;
        float f[4] = {v.x, v.y, v.z, v.w};
        for (int j = 0; j < 4; j++) {
            __bf16 h = (__bf16)f[j];
            hv[j] = h;
            lv[j] = (__bf16)(f[j] - (float)h);
        }
        int boff = row * 128 + ((kq * 2) ^ ((row & 7) << 4));
        *reinterpret_cast<bf16x4*>(L + OFF_A_HI + boff) = hv;
        *reinterpret_cast<bf16x4*>(L + OFF_A_LO + boff) = lv;
    }
    // ---- stage B (Wt hi/lo, already transposed+split in global) ----
    {
        const char* gh = (const char*)(WtHi + (size_t)r * 4096);
        const char* gl = (const char*)(WtLo + (size_t)r * 4096);
        for (int rep = 0; rep < 2; rep++) {
            int idx = rep * 256 + t;           // 512 chunks x 16B = 8KB
            int c = idx >> 3;
            int ko = (idx & 7) * 16;
            int boff = c * 128 + (ko ^ ((c & 7) << 4));
            *reinterpret_cast<uint4*>(L + OFF_B_HI + boff) =
                *reinterpret_cast<const uint4*>(gh + idx * 16);
            *reinterpret_cast<uint4*>(L + OFF_B_LO + boff) =
                *reinterpret_cast<const uint4*>(gl + idx * 16);
        }
        // attW hi tile: 32 rows x 128B = 4KB
        const char* ga = (const char*)attWHi;
        int c = t >> 3;
        int ko = (t & 7) * 16;
        int boff = c * 128 + (ko ^ ((c & 7) << 4));
        *reinterpret_cast<uint4*>(L + OFF_ATTW + boff) =
            *reinterpret_cast<const uint4*>(ga + t * 16);
    }
    __syncthreads();

    int w = t >> 6, l = t & 63;
    int lrow = l & 15, lg = l >> 4;
    int swz = (lrow & 7) << 4;

    // ---- GEMM: 16 rows per wave x 64 cols, K=64, split-bf16 ----
    f32x4 acc[4] = {{0.f, 0.f, 0.f, 0.f}, {0.f, 0.f, 0.f, 0.f},
                    {0.f, 0.f, 0.f, 0.f}, {0.f, 0.f, 0.f, 0.f}};
    #pragma unroll
    for (int kk = 0; kk < 2; kk++) {
        int koff = (kk * 32 + lg * 8) * 2;
        int aoff = (16 * w + lrow) * 128 + (koff ^ swz);
        bf16x8 ahi = *reinterpret_cast<const bf16x8*>(L + OFF_A_HI + aoff);
        bf16x8 alo = *reinterpret_cast<const bf16x8*>(L + OFF_A_LO + aoff);
        #pragma unroll
        for (int c = 0; c < 4; c++) {
            int boff = (16 * c + lrow) * 128 + (koff ^ swz);
            bf16x8 bhi = *reinterpret_cast<const bf16x8*>(L + OFF_B_HI + boff);
            bf16x8 blo = *reinterpret_cast<const bf16x8*>(L + OFF_B_LO + boff);
            acc[c] = __builtin_amdgcn_mfma_f32_16x16x32_bf16(ahi, bhi, acc[c], 0, 0, 0);
            acc[c] = __builtin_amdgcn_mfma_f32_16x16x32_bf16(ahi, blo, acc[c], 0, 0, 0);
            acc[c] = __builtin_amdgcn_mfma_f32_16x16x32_bf16(alo, bhi, acc[c], 0, 0, 0);
        }
    }
    __syncthreads();   // all frag reads done before h_stage overwrites A/B

    // ---- bias + relu, write fp32 h to LDS stage ----
    #pragma unroll
    for (int c = 0; c < 4; c++) {
        int col = 16 * c + lrow;
        float bv = bias[r * D + col];
        #pragma unroll
        for (int reg = 0; reg < 4; reg++) {
            int row = 16 * w + lg * 4 + reg;
            hs[row * 68 + col] = fmaxf(acc[c][reg] + bv, 0.f);
        }
    }
    __syncthreads();

    // ---- coalesced global store of h ----
    for (int jj = 0; jj < 4; jj++) {
        int idx = jj * 256 + t;
        int row = idx >> 4;
        int sg = (idx & 15) * 4;
        if (n0 + row < N) {
            float4 v = *reinterpret_cast<const float4*>(&hs[row * 68 + sg]);
            *reinterpret_cast<float4*>(&hbuf[((size_t)(n0 + row) * R + r) * D + sg]) = v;
        }
    }

    // ---- score: s = sum_m tanh(h @ attW + attb)_m * attv_m  (bf16-hi precision) ----
    f32x4 sacc[2] = {{0.f, 0.f, 0.f, 0.f}, {0.f, 0.f, 0.f, 0.f}};
    #pragma unroll
    for (int kk = 0; kk < 2; kk++) {
        int hrow = 16 * w + lrow;
        const float* hp = hs + hrow * 68 + kk * 32 + lg * 8;
        float4 f0 = *reinterpret_cast<const float4*>(hp);
        float4 f1 = *reinterpret_cast<const float4*>(hp + 4);
        bf16x8 ha;
        ha[0] = (__bf16)f0.x; ha[1] = (__bf16)f0.y; ha[2] = (__bf16)f0.z; ha[3] = (__bf16)f0.w;
        ha[4] = (__bf16)f1.x; ha[5] = (__bf16)f1.y; ha[6] = (__bf16)f1.z; ha[7] = (__bf16)f1.w;
        int koff = (kk * 32 + lg * 8) * 2;
        #pragma unroll
        for (int c = 0; c < 2; c++) {
            int boff = (16 * c + lrow) * 128 + (koff ^ swz);
            bf16x8 bw = *reinterpret_cast<const bf16x8*>(L + OFF_ATTW + boff);
            sacc[c] = __builtin_amdgcn_mfma_f32_16x16x32_bf16(ha, bw, sacc[c], 0, 0, 0);
        }
    }
    float tot = 0.f;
    #pragma unroll
    for (int c = 0; c < 2; c++) {
        int m = 16 * c + lrow;
        float ab = attb[m], av = attv[m];
        #pragma unroll
        for (int reg = 0; reg < 4; reg++) {
            int node = n0 + 16 * w + lg * 4 + reg;
            float tv = tanhf(sacc[c][reg] + ab) * av;
            tot += (node < N) ? tv : 0.f;
        }
    }
    for (int o = 1; o < 64; o <<= 1) tot += __shfl_xor(tot, o);
    if (l == 0) atomicAdd(&wspread[r * 1024 + (blockIdx.x & 1023)], tot);
}

__global__ void k_beta(const float* __restrict__ wspread, float* __restrict__ beta, int N) {
    __shared__ float sums[4];
    int wid = threadIdx.x >> 6, lane = threadIdx.x & 63;
    float s = 0.f;
    for (int i = lane; i < 1024; i += 64) s += wspread[wid * 1024 + i];
    for (int o = 32; o > 0; o >>= 1) s += __shfl_down(s, o);
    if (lane == 0) sums[wid] = s;
    __syncthreads();
    if (threadIdx.x == 0) {
        float mean[R], m = -1e30f;
        for (int r = 0; r < R; r++) { mean[r] = sums[r] / (float)N; m = fmaxf(m, mean[r]); }
        float e[R], tot = 0.f;
        for (int r = 0; r < R; r++) { e[r] = expf(mean[r] - m); tot += e[r]; }
        for (int r = 0; r < R; r++) beta[r] = e[r] / tot;
    }
}

__global__ void k_combine(const float* __restrict__ h, const float* __restrict__ beta,
                          float* __restrict__ out, int N) {
    int idx = blockIdx.x * blockDim.x + threadIdx.x;
    int n = idx >> 4, q = idx & 15;
    if (n >= N) return;
    float b0 = beta[0], b1 = beta[1], b2 = beta[2], b3 = beta[3];
    const float4* hp = reinterpret_cast<const float4*>(&h[(size_t)n * R * D]);
    float4 v0 = hp[q], v1 = hp[16 + q], v2 = hp[32 + q], v3 = hp[48 + q];
    float4 o;
    o.x = b0 * v0.x + b1 * v1.x + b2 * v2.x + b3 * v3.x;
    o.y = b0 * v0.y + b1 * v1.y + b2 * v2.y + b3 * v3.y;
    o.z = b0 * v0.z + b1 * v1.z + b2 * v2.z + b3 * v3.z;
    o.w = b0 * v0.w + b1 * v1.w + b2 * v2.w + b3 * v3.w;
    reinterpret_cast<float4*>(out)[idx] = o;
}

extern "C" void kernel_launch(void* const* d_in, const int* in_sizes, int n_in,
                              void* d_out, int out_size, void* d_ws, size_t ws_size,
                              hipStream_t stream) {
    const float* x   = (const float*)d_in[0];
    const int*   src = (const int*)d_in[1];
    const int*   dst = (const int*)d_in[2];
    const float* W1  = (const float*)d_in[3];
    const float* b1  = (const float*)d_in[4];
    const float* a1W = (const float*)d_in[5];
    const float* a1b = (const float*)d_in[6];
    const float* a1v = (const float*)d_in[7];
    const float* W2  = (const float*)d_in[8];
    const float* b2  = (const float*)d_in[9];
    const float* a2W = (const float*)d_in[10];
    const float* a2b = (const float*)d_in[11];
    const float* a2v = (const float*)d_in[12];

    int N = in_sizes[0] / D;
    int E = in_sizes[1] / R;
    int RN = R * N;
    float* out = (float*)d_out;

    char* ws = (char*)d_ws;
    float* agg     = (float*)ws; ws += (size_t)N * R * D * 4;
    int*   degi    = (int*)ws;   ws += (size_t)RN * 4;
    int*   offs    = (int*)ws;   ws += (size_t)RN * 4;
    int*   esrc    = (int*)ws;   ws += (size_t)R * E * 4;
    int*   bsums   = (int*)ws;   ws += 4096;
    float* wspread = (float*)ws; ws += (size_t)R * 1024 * 4;
    float* beta    = (float*)ws; ws += 64;
    __bf16* WtHi   = (__bf16*)ws; ws += 2 * R * 4096 * 2;
    __bf16* WtLo   = (__bf16*)ws; ws += 2 * R * 4096 * 2;
    __bf16* attWHi = (__bf16*)ws; ws += 2 * 2048 * 2;
    int*   rank    = (int*)agg;  // consumed by k_fill_part before k_gather writes agg

    // ---- weight precompute ----
    k_prep<<<144, 256, 0, stream>>>(W1, W2, a1W, a2W, WtHi, WtLo, attWHi);

    // ---- CSR build ----
    hipMemsetAsync(degi, 0, (size_t)RN * 4, stream);
    k_degi_rank<<<dim3((E + 255) / 256, R), 256, 0, stream>>>(dst, degi, rank, E, N);
    int nb1024 = (RN + 1023) / 1024;
    k_scan_block<<<nb1024, 256, 0, stream>>>(degi, offs, bsums, RN);
    k_scan_bsums<<<1, 256, 0, stream>>>(bsums, nb1024);
    k_scan_add<<<(RN + 255) / 256, 256, 0, stream>>>(offs, bsums, RN);
    k_fill_part<<<NPART * 128, 256, 0, stream>>>(src, dst, rank, offs, esrc, E, N,
                                                 (float)NPART / (float)N);

    int nbg = (N + 63) / 64;
    for (int layer = 0; layer < 2; layer++) {
        const float* in = layer ? (const float*)out : x;
        const float* bb = layer ? b2 : b1;
        const float* ab = layer ? a2b : a1b;
        const float* av = layer ? a2v : a1v;
        const __bf16* wh = WtHi + (size_t)layer * 16384;
        const __bf16* wl = WtLo + (size_t)layer * 16384;
        const __bf16* aw = attWHi + (size_t)layer * 2048;

        hipMemsetAsync(wspread, 0, (size_t)R * 1024 * 4, stream);
        k_gather<<<N, 256, 0, stream>>>(in, esrc, offs, degi, agg, N);
        k_rgemm<<<dim3(nbg, R), 256, 0, stream>>>(agg, wh, wl, aw, bb, ab, av, wspread, N);
        k_beta<<<1, 256, 0, stream>>>(wspread, beta, N);
        k_combine<<<(N * 16 + 255) / 256, 256, 0, stream>>>(agg, beta, out, N);
    }
}